// Round 5
// baseline (403.777 us; speedup 1.0000x reference)
//
#include <hip/hip_runtime.h>

#define B_    128
#define P_    16
#define NP_   256
#define EP_   1280
#define EPG_  2048
#define ODIM_ 256
#define NH_   128

typedef __attribute__((ext_vector_type(8))) short s8_t;
typedef __attribute__((ext_vector_type(4))) float f4_t;

__device__ __forceinline__ unsigned short f2b(float x) {
  unsigned u = __builtin_bit_cast(unsigned, x);
  u = (u + 0x7fffu + ((u >> 16) & 1u)) >> 16;
  return (unsigned short)u;
}
__device__ __forceinline__ float b2f(short x) {
  unsigned u = ((unsigned)(unsigned short)x) << 16;
  return __builtin_bit_cast(float, u);
}

// ws layout (float offsets):
//   rep    @ 0       : 65536 f   [128][512]
//   sq     @ 65536   : 2048 f    per-graph recon partial sums
//   ftT    @ 67584   : 98304 sh  [n(128)][k(768)] bf16
//   gcT    @ 116736  : 49152 sh  [l][n(128)][k(128)] bf16
//   c1T    @ 141312  : 8192 sh   [n(64)][k(128)] bf16
//   abar   @ 145408  : 16384 sh  [d(128)][s(128)] bf16
// total 153600 floats = 614 KB

// ---------------------------------------------------------------------------
// Stage A: blocks 0..2047 = plane graphs; blocks 2048..2056 = prep roles
// (weight transpose/convert + Abar build) hidden under the plane wave.
// ---------------------------------------------------------------------------
struct SmemA {
  float f[256];
  float S0a[256], S1a[256];
  float el2[256], er2[256];
  float abg0[128], abg1[128], abg2[128];
  float al2v[32], ar2v[32];
  __align__(16) unsigned short wT[64 * 136];
  __align__(16) unsigned short z2[256 * 40];
  int cnt[256]; int wtot[4];
  unsigned short esrc[1280];
  float redf[512];
  float scA[32], shA[32];
  float dscA[64], dshA[64];
  float dW2v[128];
  float r8[4][8]; float stat[8]; float wA[2], wB[2];
  float rlacc;
};

__global__ __launch_bounds__(256, 3) void plane_enc(
    const float* __restrict__ feat, const int* __restrict__ esrcg, const int* __restrict__ edstg,
    const float* __restrict__ W1, const float* __restrict__ al1, const float* __restrict__ ar1,
    const float* __restrict__ res1, const float* __restrict__ b1, const float* __restrict__ g1,
    const float* __restrict__ be1,
    const float* __restrict__ W2, const float* __restrict__ al2, const float* __restrict__ ar2,
    const float* __restrict__ res2, const float* __restrict__ g2, const float* __restrict__ be2,
    const float* __restrict__ dW1, const float* __restrict__ dg, const float* __restrict__ dbe,
    const float* __restrict__ dW2, const float* __restrict__ db2,
    const float* __restrict__ ftW, const float* __restrict__ gcW, const float* __restrict__ c1W,
    const int* __restrict__ ps, const int* __restrict__ pd, const int* __restrict__ mask,
    float* __restrict__ ws)
{
  __shared__ SmemA s;
  const int g = blockIdx.x;
  const int t = threadIdx.x;

  // ---- prep roles (run concurrently with plane blocks) ---------------------
  if (g >= 2048) {
    const int role = g - 2048;
    unsigned short* ftT  = (unsigned short*)(ws + 67584);
    unsigned short* gcT  = (unsigned short*)(ws + 116736);
    unsigned short* c1T  = (unsigned short*)(ws + 141312);
    unsigned short* abar = (unsigned short*)(ws + 145408);
    if (role < 6) {              // ftT chunk: k in [role*128, role*128+128)
      for (int idx = t; idx < 16384; idx += 256) {
        int k = role * 128 + (idx >> 7), n = idx & 127;
        ftT[n * 768 + k] = f2b(ftW[k * 128 + n]);
      }
    } else if (role == 6) {      // gcW all 3 layers
      for (int idx = t; idx < 49152; idx += 256) {
        int l = idx >> 14, r = idx & 16383, k = r >> 7, n = r & 127;
        gcT[l * 16384 + n * 128 + k] = f2b(gcW[l * 16384 + k * 128 + n]);
      }
    } else if (role == 7) {      // c1W
      for (int idx = t; idx < 8192; idx += 256) {
        int k = idx >> 6, n = idx & 63;
        c1T[n * 128 + k] = f2b(c1W[k * 64 + n]);
      }
    } else {                     // Abar build (packed 2x16-bit counts in LDS)
      unsigned* cnt2 = (unsigned*)&s;        // [8192] = 32 KB
      int* co = (int*)(cnt2 + 8192);
      int* ci = co + 128;
      float* facs = (float*)(ci + 128);
      float* facd = facs + 128;
      for (int idx = t; idx < 8192; idx += 256) cnt2[idx] = 0u;
      if (t < 128) { co[t] = 0; ci[t] = 0; }
      __syncthreads();
      for (int e = t; e < EPG_; e += 256) {
        int sN = ps[e], d = pd[e];
        atomicAdd(&co[sN], 1); atomicAdd(&ci[d], 1);
        int pair = d * 128 + sN;
        atomicAdd(&cnt2[pair >> 1], 1u << ((pair & 1) * 16));
      }
      __syncthreads();
      if (t < 128) {
        float mk = (float)mask[t];
        int da = co[t] > 1 ? co[t] : 1;
        int db = ci[t] > 1 ? ci[t] : 1;
        facs[t] = mk * rsqrtf((float)da);
        facd[t] = mk * rsqrtf((float)db);
      }
      __syncthreads();
      for (int idx = t; idx < 16384; idx += 256) {
        int d = idx >> 7, sN = idx & 127;
        unsigned cc = (cnt2[idx >> 1] >> ((idx & 1) * 16)) & 0xffffu;
        abar[idx] = f2b((float)cc * facd[d] * facs[sN]);
      }
    }
    return;
  }

  const int p = g & 15;
  const int lane = t & 63, wv = t >> 6;
  const int l15 = lane & 15, quad = lane >> 4;
  float* rep_out = ws;
  float* sq_out  = ws + 65536;

  s.f[t] = feat[g * NP_ + t];
  if (t < 32) { s.al2v[t] = al2[p * 32 + t]; s.ar2v[t] = ar2[p * 32 + t]; }
  if (t == 0) s.rlacc = 0.f;
  s.cnt[t] = 0;
  __syncthreads();

  const int* gs = esrcg + g * EP_;
  const int* gd = edstg + g * EP_;
  for (int k = t; k < EP_; k += 256) atomicAdd(&s.cnt[gd[k]], 1);
  __syncthreads();
  int v = s.cnt[t];
  int incl = v;
  #pragma unroll
  for (int off = 1; off < 64; off <<= 1) {
    int n = __shfl_up(incl, off, 64);
    if (lane >= off) incl += n;
  }
  if (lane == 63) s.wtot[wv] = incl;
  __syncthreads();
  int woff = 0;
  for (int w = 0; w < wv; w++) woff += s.wtot[w];
  const int myStart = woff + incl - v;
  const int myDeg = v;
  __syncthreads();
  s.cnt[t] = myStart;
  __syncthreads();
  for (int k = t; k < EP_; k += 256) {
    int d = gd[k];
    int pos = atomicAdd(&s.cnt[d], 1);
    s.esrc[pos] = (unsigned short)gs[k];
  }
  {
    const float* W2g = W2 + p * 4096;
    const float* Rg  = res2 + p * 4096;
    for (int q = 0; q < 16; q++) {
      int idx = t + 256 * q;
      int k = idx >> 5, n = idx & 31;
      s.wT[n * 136 + k]        = f2b(W2g[idx]);
      s.wT[(n + 32) * 136 + k] = f2b(Rg[idx]);
    }
  }
  if (t < 128) {
    float w1v = W1[p * 128 + t];
    s.el2[t] = w1v * al1[p * 128 + t];
    s.er2[t] = w1v * ar1[p * 128 + t];
  }
  __syncthreads();
  if (t < 2) {
    float a = 0.f, bq = 0.f;
    for (int d2 = 0; d2 < 64; d2++) { a += s.el2[t * 64 + d2]; bq += s.er2[t * 64 + d2]; }
    s.wA[t] = a; s.wB[t] = bq;
  }
  __syncthreads();

  const float fi = s.f[t];
  float S0, S1;
  {
    const float wa0 = s.wA[0], wb0 = s.wB[0], wa1 = s.wA[1], wb1 = s.wB[1];
    float m0 = -1e30f, m1 = -1e30f;
    for (int j = 0; j < myDeg; j++) {
      float fs = s.f[s.esrc[myStart + j]];
      float e0 = wa0 * fs + wb0 * fi; e0 = e0 > 0.f ? e0 : 0.2f * e0;
      float e1 = wa1 * fs + wb1 * fi; e1 = e1 > 0.f ? e1 : 0.2f * e1;
      m0 = fmaxf(m0, e0); m1 = fmaxf(m1, e1);
    }
    float ss0 = 0.f, ss1 = 0.f, U0 = 0.f, U1 = 0.f;
    for (int j = 0; j < myDeg; j++) {
      float fs = s.f[s.esrc[myStart + j]];
      float e0 = wa0 * fs + wb0 * fi; e0 = e0 > 0.f ? e0 : 0.2f * e0;
      float e1 = wa1 * fs + wb1 * fi; e1 = e1 > 0.f ? e1 : 0.2f * e1;
      float x0 = __expf(e0 - m0), x1 = __expf(e1 - m1);
      ss0 += x0; U0 += x0 * fs;
      ss1 += x1; U1 += x1 * fs;
    }
    S0 = U0 / (ss0 + 1e-9f);
    S1 = U1 / (ss1 + 1e-9f);
    s.S0a[t] = S0; s.S1a[t] = S1;
  }

  {
    float vals[8] = {fi, fi * fi, S0, S0 * S0, S0 * fi, S1, S1 * S1, S1 * fi};
    #pragma unroll
    for (int d2 = 32; d2 > 0; d2 >>= 1) {
      #pragma unroll
      for (int q = 0; q < 8; q++) vals[q] += __shfl_down(vals[q], d2, 64);
    }
    if (lane == 0) {
      #pragma unroll
      for (int q = 0; q < 8; q++) s.r8[wv][q] = vals[q];
    }
  }
  __syncthreads();
  if (t < 8) s.stat[t] = (s.r8[0][t] + s.r8[1][t] + s.r8[2][t] + s.r8[3][t]) * (1.f / 256.f);
  __syncthreads();
  if (t < 128) {
    float mf = s.stat[0], ef2 = s.stat[1];
    int hh = t >> 6;
    float mS = s.stat[2 + 3 * hh], eS2 = s.stat[3 + 3 * hh], eSf = s.stat[4 + 3 * hh];
    float varS = eS2 - mS * mS, varf = ef2 - mf * mf, cov = eSf - mS * mf;
    float Wv = W1[p * 128 + t], Rv = res1[p * 128 + t], Bv = b1[p * 128 + t];
    float mu  = Wv * mS + Rv * mf + Bv;
    float var = Wv * Wv * varS + Rv * Rv * varf + 2.f * Wv * Rv * cov;
    float gn  = g1[p * 128 + t] * rsqrtf(var + 1e-5f);
    s.abg0[t] = gn * Wv;
    s.abg1[t] = gn * Rv;
    s.abg2[t] = gn * (Bv - mu) + be1[p * 128 + t];
  }
  __syncthreads();

  float resv[32];
  {
    f4_t accum[4][4];
    #pragma unroll
    for (int i = 0; i < 4; i++)
      #pragma unroll
      for (int nt = 0; nt < 4; nt++) accum[i][nt] = (f4_t){0.f, 0.f, 0.f, 0.f};

    float fm[4], s0m[4], s1m[4];
    #pragma unroll
    for (int i = 0; i < 4; i++) {
      int m = (wv * 4 + i) * 16 + l15;
      fm[i] = s.f[m]; s0m[i] = s.S0a[m]; s1m[i] = s.S1a[m];
    }
    #pragma unroll
    for (int kt = 0; kt < 4; kt++) {
      int cbase = kt * 32 + quad * 8;
      float a0[8], a1[8], a2[8];
      #pragma unroll
      for (int j = 0; j < 8; j++) {
        a0[j] = s.abg0[cbase + j]; a1[j] = s.abg1[cbase + j]; a2[j] = s.abg2[cbase + j];
      }
      s8_t afr[4];
      #pragma unroll
      for (int i = 0; i < 4; i++) {
        float Sm = (kt < 2) ? s0m[i] : s1m[i];
        union { s8_t v; unsigned short u[8]; } fu;
        #pragma unroll
        for (int j = 0; j < 8; j++) {
          float h = fmaxf(fmaf(a0[j], Sm, fmaf(a1[j], fm[i], a2[j])), 0.f);
          fu.u[j] = f2b(h);
        }
        afr[i] = fu.v;
      }
      s8_t bfr[4];
      #pragma unroll
      for (int nt = 0; nt < 4; nt++)
        bfr[nt] = *(const s8_t*)&s.wT[(nt * 16 + l15) * 136 + cbase];
      #pragma unroll
      for (int i = 0; i < 4; i++)
        #pragma unroll
        for (int nt = 0; nt < 4; nt++)
          accum[i][nt] = __builtin_amdgcn_mfma_f32_16x16x32_bf16(afr[i], bfr[nt], accum[i][nt], 0, 0, 0);
    }
    #pragma unroll
    for (int i = 0; i < 4; i++) {
      int mBase = (wv * 4 + i) * 16 + quad * 4;
      #pragma unroll
      for (int nt = 0; nt < 2; nt++) {
        int col = nt * 16 + l15;
        #pragma unroll
        for (int r = 0; r < 4; r++)
          s.z2[(mBase + r) * 40 + col] = f2b(accum[i][nt][r]);
      }
      #pragma unroll
      for (int h2 = 0; h2 < 2; h2++)
        #pragma unroll
        for (int r = 0; r < 4; r++)
          resv[(i * 2 + h2) * 4 + r] = accum[i][2 + h2][r];
    }
  }
  __syncthreads();

  {
    const s8_t* zr = (const s8_t*)&s.z2[t * 40];
    float el = 0.f, er = 0.f;
    #pragma unroll
    for (int q = 0; q < 4; q++) {
      s8_t vz = zr[q];
      #pragma unroll
      for (int j = 0; j < 8; j++) {
        float zv = b2f(vz[j]);
        el += zv * s.al2v[q * 8 + j];
        er += zv * s.ar2v[q * 8 + j];
      }
    }
    s.el2[t] = el; s.er2[t] = er;
  }
  {
    const float* Dg = dW1 + p * 4096;
    for (int q = 0; q < 16; q++) {
      int idx = t + 256 * q;
      int k = idx >> 7, n = idx & 127;
      s.wT[n * 40 + k] = f2b(Dg[idx]);
    }
    if (t < 128) s.dW2v[t] = dW2[p * 128 + t];
  }
  const float db2v = db2[p];
  __syncthreads();

  float hrow[32];
  {
    const float eri = s.er2[t];
    float m = -1e30f;
    for (int j = 0; j < myDeg; j++) {
      float e = s.el2[s.esrc[myStart + j]] + eri;
      e = e > 0.f ? e : 0.2f * e;
      m = fmaxf(m, e);
    }
    float ss = 0.f;
    #pragma unroll
    for (int d2 = 0; d2 < 32; d2++) hrow[d2] = 0.f;
    for (int j = 0; j < myDeg; j++) {
      int sj = s.esrc[myStart + j];
      float e = s.el2[sj] + eri;
      e = e > 0.f ? e : 0.2f * e;
      float x = __expf(e - m);
      ss += x;
      const s8_t* zr = (const s8_t*)&s.z2[sj * 40];
      #pragma unroll
      for (int q = 0; q < 4; q++) {
        s8_t vz = zr[q];
        #pragma unroll
        for (int jj = 0; jj < 8; jj++) hrow[q * 8 + jj] += x * b2f(vz[jj]);
      }
    }
    float inv = 1.f / (ss + 1e-9f);
    #pragma unroll
    for (int d2 = 0; d2 < 32; d2++) hrow[d2] *= inv;
  }
  __syncthreads();
  #pragma unroll
  for (int i = 0; i < 4; i++) {
    int mBase = (wv * 4 + i) * 16 + quad * 4;
    #pragma unroll
    for (int h2 = 0; h2 < 2; h2++) {
      int col = h2 * 16 + l15;
      #pragma unroll
      for (int r = 0; r < 4; r++)
        s.z2[(mBase + r) * 40 + col] = f2b(resv[(i * 2 + h2) * 4 + r]);
    }
  }
  __syncthreads();
  {
    const s8_t* zr = (const s8_t*)&s.z2[t * 40];
    #pragma unroll
    for (int q = 0; q < 4; q++) {
      s8_t vz = zr[q];
      #pragma unroll
      for (int jj = 0; jj < 8; jj++) hrow[q * 8 + jj] += b2f(vz[jj]);
    }
  }
  #pragma unroll
  for (int d2 = 0; d2 < 32; d2++) s.z2[t * 40 + d2] = f2b(hrow[d2]);
  __syncthreads();

  {
    int c = t & 31, gq = t >> 5;
    float s1 = 0.f, s2 = 0.f;
    for (int j = 0; j < 32; j++) {
      float vz = b2f((short)s.z2[(gq * 32 + j) * 40 + c]);
      s1 += vz; s2 += vz * vz;
    }
    s.redf[t] = s1; s.redf[256 + t] = s2;
  }
  __syncthreads();
  if (t < 32) {
    float s1 = 0.f, s2 = 0.f;
    #pragma unroll
    for (int q = 0; q < 8; q++) { s1 += s.redf[q * 32 + t]; s2 += s.redf[256 + q * 32 + t]; }
    float mu = s1 * (1.f / 256.f);
    float var = s2 * (1.f / 256.f) - mu * mu;
    float a = g2[p * 32 + t] * rsqrtf(var + 1e-5f);
    s.scA[t] = a; s.shA[t] = be2[p * 32 + t] - a * mu;
  }
  __syncthreads();
  {
    int c = t & 31, gq = t >> 5;
    float a = s.scA[c], bb = s.shA[c];
    float s1 = 0.f;
    for (int j = 0; j < 32; j++) {
      int ad = (gq * 32 + j) * 40 + c;
      float vz = b2f((short)s.z2[ad]);
      float hv = fmaxf(a * vz + bb, 0.f);
      s.z2[ad] = f2b(hv);
      s1 += hv;
    }
    s.redf[t] = s1;
  }
  __syncthreads();
  if (t < 32) {
    float s1 = 0.f;
    #pragma unroll
    for (int q = 0; q < 8; q++) s1 += s.redf[q * 32 + t];
    rep_out[g * 32 + t] = s1 * (1.f / 256.f);
  }
  __syncthreads();

  {
    s8_t afr2[4];
    #pragma unroll
    for (int i = 0; i < 4; i++)
      afr2[i] = *(const s8_t*)&s.z2[((wv * 4 + i) * 16 + l15) * 40 + quad * 8];
    float rAcc[4][4];
    #pragma unroll
    for (int i = 0; i < 4; i++)
      #pragma unroll
      for (int r = 0; r < 4; r++) rAcc[i][r] = 0.f;

    for (int half = 0; half < 2; half++) {
      __syncthreads();
      s.redf[t] = 0.f; s.redf[256 + t] = 0.f;
      __syncthreads();
      f4_t acc2[4][4];
      #pragma unroll
      for (int i = 0; i < 4; i++)
        #pragma unroll
        for (int nt = 0; nt < 4; nt++) acc2[i][nt] = (f4_t){0.f, 0.f, 0.f, 0.f};
      s8_t bfr[4];
      #pragma unroll
      for (int nt = 0; nt < 4; nt++)
        bfr[nt] = *(const s8_t*)&s.wT[(half * 64 + nt * 16 + l15) * 40 + quad * 8];
      #pragma unroll
      for (int i = 0; i < 4; i++)
        #pragma unroll
        for (int nt = 0; nt < 4; nt++)
          acc2[i][nt] = __builtin_amdgcn_mfma_f32_16x16x32_bf16(afr2[i], bfr[nt], acc2[i][nt], 0, 0, 0);
      #pragma unroll
      for (int nt = 0; nt < 4; nt++) {
        float s1 = 0.f, s2 = 0.f;
        #pragma unroll
        for (int i = 0; i < 4; i++)
          #pragma unroll
          for (int r = 0; r < 4; r++) { float vv = acc2[i][nt][r]; s1 += vv; s2 += vv * vv; }
        atomicAdd(&s.redf[nt * 16 + l15], s1);
        atomicAdd(&s.redf[256 + nt * 16 + l15], s2);
      }
      __syncthreads();
      if (t < 64) {
        int col = half * 64 + t;
        float mu = s.redf[t] * (1.f / 256.f);
        float var = s.redf[256 + t] * (1.f / 256.f) - mu * mu;
        float a = dg[p * 128 + col] * rsqrtf(var + 1e-5f);
        s.dscA[t] = a; s.dshA[t] = dbe[p * 128 + col] - a * mu;
      }
      __syncthreads();
      #pragma unroll
      for (int nt = 0; nt < 4; nt++) {
        int cl = nt * 16 + l15;
        float a = s.dscA[cl], bb = s.dshA[cl], w2 = s.dW2v[half * 64 + cl];
        #pragma unroll
        for (int i = 0; i < 4; i++)
          #pragma unroll
          for (int r = 0; r < 4; r++) {
            float dv = fmaxf(a * acc2[i][nt][r] + bb, 0.f);
            rAcc[i][r] += dv * w2;
          }
      }
    }
    #pragma unroll
    for (int off = 1; off < 16; off <<= 1)
      #pragma unroll
      for (int i = 0; i < 4; i++)
        #pragma unroll
        for (int r = 0; r < 4; r++) rAcc[i][r] += __shfl_xor(rAcc[i][r], off, 64);
    if (l15 == 0) {
      float sq = 0.f;
      #pragma unroll
      for (int i = 0; i < 4; i++)
        #pragma unroll
        for (int r = 0; r < 4; r++) {
          int m = (wv * 4 + i) * 16 + quad * 4 + r;
          float diff = rAcc[i][r] + db2v - s.f[m];
          sq += diff * diff;
        }
      atomicAdd(&s.rlacc, sq);
    }
  }
  __syncthreads();
  if (t == 0) sq_out[g] = s.rlacc;
}

// ---------------------------------------------------------------------------
// Patient stage v3: ONE block, 1024 threads. All static matmul operands
// (ftT/gcT/c1T/abar, bf16, pre-transposed by prep blocks) are loaded DIRECTLY
// from global as 16B/lane fragments — no LDS staging, no conversion, no
// per-chunk barriers. LDS only for hT/aggB (produced in-kernel) + reductions.
// ---------------------------------------------------------------------------
struct SmemB {
  __align__(16) unsigned short hT[128 * 136];     // h^T bf16 [feature][patient]
  union {
    __align__(16) unsigned short aggB[128 * 136]; // A-operand (agg / hsum/4)
    float zF[128 * 68];                           // cls pre-LN (same bytes)
  } u;
  float redA[1024], redB[1024];
  float scB[128], shB[128];
  float rsum[16];
};

__global__ __launch_bounds__(1024) void k_patient(
    const float* __restrict__ orig, const float* __restrict__ ws_ro,
    const float* __restrict__ ftg, const float* __restrict__ ftbe,
    const float* __restrict__ gbng, const float* __restrict__ gbnbe,
    const float* __restrict__ c1b,
    const float* __restrict__ lng, const float* __restrict__ lnbe,
    const float* __restrict__ c2W, const float* __restrict__ c2b,
    float* __restrict__ out)
{
  __shared__ SmemB s;
  const int t = threadIdx.x;
  const int w = t >> 6, lane = t & 63;
  const int l15 = lane & 15, quad = lane >> 4;
  const int mb = w & 7, nb = (w >> 3) * 64;

  const float* rep = ws_ro;
  const float* sq  = ws_ro + 65536;
  const unsigned short* ftT  = (const unsigned short*)(ws_ro + 67584);
  const unsigned short* gcT  = (const unsigned short*)(ws_ro + 116736);
  const unsigned short* c1T  = (const unsigned short*)(ws_ro + 141312);
  const unsigned short* abar = (const unsigned short*)(ws_ro + 145408);

  // rloss reduction (2048 partials)
  {
    float v = sq[t] + sq[t + 1024];
    #pragma unroll
    for (int d2 = 32; d2 > 0; d2 >>= 1) v += __shfl_down(v, d2, 64);
    if (lane == 0) s.rsum[w] = v;
  }

  // ---- ft matmul: M=128 N=128 K=768, B direct from global ------------------
  f4_t acc[4];
  #pragma unroll
  for (int nt = 0; nt < 4; nt++) acc[nt] = (f4_t){0.f, 0.f, 0.f, 0.f};
  const int m = mb * 16 + l15;
  #pragma unroll 1
  for (int chunk = 0; chunk < 6; chunk++) {
    #pragma unroll
    for (int ks = 0; ks < 4; ks++) {
      int k0 = chunk * 128 + ks * 32 + quad * 8;
      const float* px = (k0 < 256) ? (orig + m * 256 + k0) : (rep + m * 512 + (k0 - 256));
      float4 xa = ((const float4*)px)[0];
      float4 xb = ((const float4*)px)[1];
      union { s8_t v; unsigned short u[8]; } fu;
      fu.u[0] = f2b(xa.x); fu.u[1] = f2b(xa.y); fu.u[2] = f2b(xa.z); fu.u[3] = f2b(xa.w);
      fu.u[4] = f2b(xb.x); fu.u[5] = f2b(xb.y); fu.u[6] = f2b(xb.z); fu.u[7] = f2b(xb.w);
      #pragma unroll
      for (int nt = 0; nt < 4; nt++) {
        s8_t bfr = *(const s8_t*)&ftT[(nb + nt * 16 + l15) * 768 + k0];
        acc[nt] = __builtin_amdgcn_mfma_f32_16x16x32_bf16(fu.v, bfr, acc[nt], 0, 0, 0);
      }
    }
  }

  // ---- BN(ft) + relu -> h regs + hT ----------------------------------------
  float hR[16], hsumR[16];
  #pragma unroll
  for (int nt = 0; nt < 4; nt++) {
    float s1 = acc[nt][0] + acc[nt][1] + acc[nt][2] + acc[nt][3];
    float s2 = acc[nt][0]*acc[nt][0] + acc[nt][1]*acc[nt][1] + acc[nt][2]*acc[nt][2] + acc[nt][3]*acc[nt][3];
    s1 += __shfl_xor(s1, 16, 64); s1 += __shfl_xor(s1, 32, 64);
    s2 += __shfl_xor(s2, 16, 64); s2 += __shfl_xor(s2, 32, 64);
    if (quad == 0) {
      s.redA[mb * 128 + nb + nt * 16 + l15] = s1;
      s.redB[mb * 128 + nb + nt * 16 + l15] = s2;
    }
  }
  __syncthreads();
  if (t < 128) {
    float a1 = 0.f, a2 = 0.f;
    #pragma unroll
    for (int q = 0; q < 8; q++) { a1 += s.redA[q * 128 + t]; a2 += s.redB[q * 128 + t]; }
    float mu = a1 * (1.f / 128.f), var = a2 * (1.f / 128.f) - mu * mu;
    float a = ftg[t] * rsqrtf(var + 1e-5f);
    s.scB[t] = a; s.shB[t] = ftbe[t] - a * mu;
  }
  __syncthreads();
  #pragma unroll
  for (int nt = 0; nt < 4; nt++) {
    int col = nb + nt * 16 + l15;
    float a = s.scB[col], bb = s.shB[col];
    #pragma unroll
    for (int r = 0; r < 4; r++) {
      int row = mb * 16 + quad * 4 + r;
      float hv = fmaxf(a * acc[nt][r] + bb, 0.f);
      hR[nt * 4 + r] = hv; hsumR[nt * 4 + r] = hv;
      s.hT[col * 136 + row] = f2b(hv);
    }
  }
  __syncthreads();

  // ---- 3 GC layers ---------------------------------------------------------
  #pragma unroll 1
  for (int layer = 0; layer < 3; layer++) {
    f4_t ag[4];
    #pragma unroll
    for (int nt = 0; nt < 4; nt++) ag[nt] = (f4_t){0.f, 0.f, 0.f, 0.f};
    #pragma unroll
    for (int ks = 0; ks < 4; ks++) {
      s8_t afr = *(const s8_t*)&abar[(mb * 16 + l15) * 128 + ks * 32 + quad * 8];
      #pragma unroll
      for (int nt = 0; nt < 4; nt++) {
        s8_t bfr = *(const s8_t*)&s.hT[(nb + nt * 16 + l15) * 136 + ks * 32 + quad * 8];
        ag[nt] = __builtin_amdgcn_mfma_f32_16x16x32_bf16(afr, bfr, ag[nt], 0, 0, 0);
      }
    }
    #pragma unroll
    for (int nt = 0; nt < 4; nt++) {
      int col = nb + nt * 16 + l15;
      #pragma unroll
      for (int r = 0; r < 4; r++)
        s.u.aggB[(mb * 16 + quad * 4 + r) * 136 + col] = f2b(ag[nt][r]);
    }
    __syncthreads();
    f4_t oc[4];
    #pragma unroll
    for (int nt = 0; nt < 4; nt++) oc[nt] = (f4_t){0.f, 0.f, 0.f, 0.f};
    #pragma unroll
    for (int ks = 0; ks < 4; ks++) {
      s8_t afr = *(const s8_t*)&s.u.aggB[(mb * 16 + l15) * 136 + ks * 32 + quad * 8];
      #pragma unroll
      for (int nt = 0; nt < 4; nt++) {
        s8_t bfr = *(const s8_t*)&gcT[layer * 16384 + (nb + nt * 16 + l15) * 128 + ks * 32 + quad * 8];
        oc[nt] = __builtin_amdgcn_mfma_f32_16x16x32_bf16(afr, bfr, oc[nt], 0, 0, 0);
      }
    }
    #pragma unroll
    for (int nt = 0; nt < 4; nt++) {
      float s1 = oc[nt][0] + oc[nt][1] + oc[nt][2] + oc[nt][3];
      float s2 = oc[nt][0]*oc[nt][0] + oc[nt][1]*oc[nt][1] + oc[nt][2]*oc[nt][2] + oc[nt][3]*oc[nt][3];
      s1 += __shfl_xor(s1, 16, 64); s1 += __shfl_xor(s1, 32, 64);
      s2 += __shfl_xor(s2, 16, 64); s2 += __shfl_xor(s2, 32, 64);
      if (quad == 0) {
        s.redA[mb * 128 + nb + nt * 16 + l15] = s1;
        s.redB[mb * 128 + nb + nt * 16 + l15] = s2;
      }
    }
    __syncthreads();
    if (t < 128) {
      float a1 = 0.f, a2 = 0.f;
      #pragma unroll
      for (int q = 0; q < 8; q++) { a1 += s.redA[q * 128 + t]; a2 += s.redB[q * 128 + t]; }
      float mu = a1 * (1.f / 128.f), var = a2 * (1.f / 128.f) - mu * mu;
      float a = gbng[layer * 128 + t] * rsqrtf(var + 1e-5f);
      s.scB[t] = a; s.shB[t] = gbnbe[layer * 128 + t] - a * mu;
    }
    __syncthreads();
    #pragma unroll
    for (int nt = 0; nt < 4; nt++) {
      int col = nb + nt * 16 + l15;
      float a = s.scB[col], bb = s.shB[col];
      #pragma unroll
      for (int r = 0; r < 4; r++) {
        int row = mb * 16 + quad * 4 + r;
        float hn = fmaxf(a * oc[nt][r] + bb, 0.f) + hR[nt * 4 + r];
        hR[nt * 4 + r] = hn;
        hsumR[nt * 4 + r] += hn;
        s.hT[col * 136 + row] = f2b(hn);
      }
    }
    __syncthreads();
  }

  // ---- classifier ----------------------------------------------------------
  #pragma unroll
  for (int nt = 0; nt < 4; nt++) {
    int col = nb + nt * 16 + l15;
    #pragma unroll
    for (int r = 0; r < 4; r++)
      s.u.aggB[(mb * 16 + quad * 4 + r) * 136 + col] = f2b(hsumR[nt * 4 + r] * 0.25f);
  }
  __syncthreads();
  {
    const int nb2 = (w >> 3) * 32;
    f4_t zc[2];
    #pragma unroll
    for (int nt = 0; nt < 2; nt++) zc[nt] = (f4_t){0.f, 0.f, 0.f, 0.f};
    #pragma unroll
    for (int ks = 0; ks < 4; ks++) {
      s8_t afr = *(const s8_t*)&s.u.aggB[(mb * 16 + l15) * 136 + ks * 32 + quad * 8];
      #pragma unroll
      for (int nt = 0; nt < 2; nt++) {
        s8_t bfr = *(const s8_t*)&c1T[(nb2 + nt * 16 + l15) * 128 + ks * 32 + quad * 8];
        zc[nt] = __builtin_amdgcn_mfma_f32_16x16x32_bf16(afr, bfr, zc[nt], 0, 0, 0);
      }
    }
    __syncthreads();   // aggB reads done before zF (same bytes) writes
    #pragma unroll
    for (int nt = 0; nt < 2; nt++) {
      int col = nb2 + nt * 16 + l15;
      #pragma unroll
      for (int r = 0; r < 4; r++)
        s.u.zF[(mb * 16 + quad * 4 + r) * 68 + col] = zc[nt][r] + c1b[col];
    }
  }
  __syncthreads();
  if (t < 128) {
    float s1 = 0.f, s2 = 0.f;
    #pragma unroll
    for (int j = 0; j < 64; j++) { float zv = s.u.zF[t * 68 + j]; s1 += zv; s2 += zv * zv; }
    float mu = s1 * (1.f / 64.f);
    float var = s2 * (1.f / 64.f) - mu * mu;
    float rs = rsqrtf(var + 1e-5f);
    float l0 = 0.f, l1 = 0.f;
    #pragma unroll
    for (int j = 0; j < 64; j++) {
      float zv = s.u.zF[t * 68 + j];
      float zn = fmaxf(lng[j] * (zv - mu) * rs + lnbe[j], 0.f);
      l0 += zn * c2W[j * 2];
      l1 += zn * c2W[j * 2 + 1];
    }
    out[t * 2]     = l0 + c2b[0];
    out[t * 2 + 1] = l1 + c2b[1];
  }
  if (t == 0) {
    float tot = 0.f;
    #pragma unroll
    for (int q = 0; q < 16; q++) tot += s.rsum[q];
    out[256] = tot * (1.f / (256.f * 2048.f));
  }
}

// ---------------------------------------------------------------------------
extern "C" void kernel_launch(void* const* d_in, const int* in_sizes, int n_in,
                              void* d_out, int out_size, void* d_ws, size_t ws_size,
                              hipStream_t stream) {
  (void)in_sizes; (void)n_in; (void)out_size; (void)ws_size;
  const float* plane_feat  = (const float*)d_in[0];
  const int*   plane_src   = (const int*)d_in[1];
  const int*   plane_dst   = (const int*)d_in[2];
  const int*   patient_src = (const int*)d_in[3];
  const int*   patient_dst = (const int*)d_in[4];
  const float* orig        = (const float*)d_in[5];
  const int*   mask        = (const int*)d_in[6];
  const float* W1   = (const float*)d_in[7];
  const float* al1  = (const float*)d_in[8];
  const float* ar1  = (const float*)d_in[9];
  const float* res1 = (const float*)d_in[10];
  const float* b1   = (const float*)d_in[11];
  const float* g1   = (const float*)d_in[12];
  const float* be1  = (const float*)d_in[13];
  const float* W2   = (const float*)d_in[14];
  const float* al2  = (const float*)d_in[15];
  const float* ar2  = (const float*)d_in[16];
  const float* res2 = (const float*)d_in[17];
  const float* g2   = (const float*)d_in[19];
  const float* be2  = (const float*)d_in[20];
  const float* dW1  = (const float*)d_in[21];
  const float* dg   = (const float*)d_in[23];
  const float* dbe  = (const float*)d_in[24];
  const float* dW2  = (const float*)d_in[25];
  const float* db2  = (const float*)d_in[26];
  const float* ftW  = (const float*)d_in[27];
  const float* ftg  = (const float*)d_in[29];
  const float* ftbe = (const float*)d_in[30];
  const float* gcW  = (const float*)d_in[31];
  const float* gbng = (const float*)d_in[33];
  const float* gbnbe= (const float*)d_in[34];
  const float* c1W  = (const float*)d_in[35];
  const float* c1b  = (const float*)d_in[36];
  const float* lng  = (const float*)d_in[37];
  const float* lnbe = (const float*)d_in[38];
  const float* c2W  = (const float*)d_in[39];
  const float* c2b  = (const float*)d_in[40];

  float* ws   = (float*)d_ws;
  float* outp = (float*)d_out;

  plane_enc<<<2057, 256, 0, stream>>>(plane_feat, plane_src, plane_dst,
      W1, al1, ar1, res1, b1, g1, be1, W2, al2, ar2, res2, g2, be2,
      dW1, dg, dbe, dW2, db2,
      ftW, gcW, c1W, patient_src, patient_dst, mask, ws);
  k_patient<<<1, 1024, 0, stream>>>(orig, ws, ftg, ftbe, gbng, gbnbe,
      c1b, lng, lnbe, c2W, c2b, outp);
}